// Round 3
// baseline (258.703 us; speedup 1.0000x reference)
//
#include <hip/hip_runtime.h>
#include <math.h>

#define HH 2048
#define WW 2048
#define NB 256

// softmax-expectation accumulator: running max, sum(e), sum(e*x), sum(e*y)
struct Tup { float m, z, sx, sy; };

__device__ __forceinline__ void comb(Tup& a, const Tup& b) {
  float Mn = fmaxf(a.m, b.m);
  // (m==Mn)?1:expf guard avoids (-inf)-(-inf) = NaN when merging identities
  float w1 = (a.m == Mn) ? 1.0f : expf(a.m - Mn);
  float w2 = (b.m == Mn) ? 1.0f : expf(b.m - Mn);
  a.z  = a.z  * w1 + b.z  * w2;
  a.sx = a.sx * w1 + b.sx * w2;
  a.sy = a.sy * w1 + b.sy * w2;
  a.m  = Mn;
}

// Online-softmax reduce of one row (WW cols). All threads get the result.
__device__ Tup row_reduce(const float* __restrict__ rowp) {
  const int tid = threadIdx.x;
  const float4* r4 = (const float4*)rowp;
  float m = -INFINITY, z = 0.0f, sx = 0.0f;
#pragma unroll
  for (int p = 0; p < WW / (4 * NB); ++p) {
    int i4 = tid + NB * p;
    float4 v = r4[i4];
    float vv[4] = {v.x, v.y, v.z, v.w};
    float c0 = (float)(i4 * 4);
#pragma unroll
    for (int k = 0; k < 4; ++k) {
      float x = vv[k] * 100.0f;   // BETA, matches reference f32 multiply
      if (x > m) {
        float sc = expf(m - x);   // first iter: expf(-inf) = 0
        z  = z  * sc + 1.0f;
        sx = sx * sc + (c0 + (float)k);
        m = x;
      } else {
        float w = expf(x - m);
        z  += w;
        sx += w * (c0 + (float)k);
      }
    }
  }
  __shared__ float sm_[NB], sz_[NB], ss_[NB];
  __syncthreads();              // WAR guard for repeated calls
  sm_[tid] = m; sz_[tid] = z; ss_[tid] = sx;
  __syncthreads();
  for (int off = NB / 2; off > 0; off >>= 1) {
    if (tid < off) {
      Tup a = {sm_[tid], sz_[tid], ss_[tid], 0.0f};
      Tup b = {sm_[tid + off], sz_[tid + off], ss_[tid + off], 0.0f};
      comb(a, b);
      sm_[tid] = a.m; sz_[tid] = a.z; ss_[tid] = a.sx;
    }
    __syncthreads();
  }
  Tup t = {sm_[0], sz_[0], ss_[0], 0.0f};
  return t;
}

__device__ Tup block_reduce4(Tup t) {
  __shared__ float am[NB], az[NB], axx[NB], ayy[NB];
  const int tid = threadIdx.x;
  __syncthreads();              // WAR guard for repeated calls
  am[tid] = t.m; az[tid] = t.z; axx[tid] = t.sx; ayy[tid] = t.sy;
  __syncthreads();
  for (int off = NB / 2; off > 0; off >>= 1) {
    if (tid < off) {
      Tup a = {am[tid], az[tid], axx[tid], ayy[tid]};
      Tup b = {am[tid + off], az[tid + off], axx[tid + off], ayy[tid + off]};
      comb(a, b);
      am[tid] = a.m; az[tid] = a.z; axx[tid] = a.sx; ayy[tid] = a.sy;
    }
    __syncthreads();
  }
  Tup r = {am[0], az[0], axx[0], ayy[0]};
  return r;
}

// Merge per-row partials arr[r], r in [s,e]; sy weight = r. All threads get result.
__device__ Tup merge_rows(const float4* arr, int s, int e) {
  Tup acc = {-INFINITY, 0.0f, 0.0f, 0.0f};
  for (int r = s + (int)threadIdx.x; r <= e; r += NB) {
    float4 p = arr[r];
    Tup q = {p.x, p.y, p.z, p.y * (float)r};
    comb(acc, q);
  }
  return block_reduce4(acc);
}

// Add analytic out-of-band complement (masked elements are exactly 0) and divide.
__device__ void finalize(Tup acc, int s, int e, bool valid, float& ax, float& ay) {
  float M = acc.m, Z = acc.z, SX = acc.sx, SY = acc.sy;
  int nin = valid ? (e - s + 1) : 0;
  int nout = HH - nin;
  if (nout > 0) {
    float M2 = fmaxf(M, 0.0f);
    float wi = (M == M2) ? 1.0f : expf(M - M2);   // M=-inf -> 0
    float wo = (M2 == 0.0f) ? 1.0f : expf(-M2);   // underflows to 0 for typical M
    Z *= wi; SX *= wi; SY *= wi;
    float nout_e = (float)nout * (float)WW;                                 // exact
    float sox = (float)nout * 2096128.0f;                                   // nout*W(W-1)/2
    float sinr = valid ? (float)(((long)(s + e) * (e - s + 1)) / 2) : 0.0f; // exact
    float soy = (2096128.0f - sinr) * 2048.0f;                              // exact
    Z  += wo * nout_e;
    SX += wo * sox;
    SY += wo * soy;
  }
  ax = SX / Z; ay = SY / Z;
}

// ws layout: [0..31] header (unused), F = 11*2048 x float4 per-row partials.

__global__ __launch_bounds__(NB) void k_rows_all(const float* __restrict__ heat,
                                                 float* ws) {
  float4* F = (float4*)(ws + 32);
  const int b = blockIdx.x;                 // 0 .. 11*HH-1 == channel*HH + row
  Tup t = row_reduce(heat + (size_t)b * WW);
  if (threadIdx.x == 0) F[b] = make_float4(t.m, t.z, t.sx, 0.0f);
}

// Single block walks the whole sequential chain over precomputed partials.
__global__ __launch_bounds__(NB) void k_chain(float* ws, float* __restrict__ out) {
  const float4* F = (const float4*)(ws + 32);
  float st[22];
  float ax, ay;

  Tup a9 = merge_rows(F + 9 * HH, 0, HH - 1);
  finalize(a9, 0, HH - 1, true, ax, ay);  st[18] = ax; st[19] = ay;   // out[9]
  Tup a10 = merge_rows(F + 10 * HH, 0, HH - 1);
  finalize(a10, 0, HH - 1, true, ax, ay); st[20] = ax; st[21] = ay;   // out[10]

  float dis = st[21] - st[19], dsum = 0.0f, dnum = 0.0f;

  for (int i = 8; i >= 0; --i) {
    float y1 = st[2 * (i + 1) + 1];
    float y2 = st[2 * (i + 2) + 1];
    float last_y = floorf(y1);
    float tmp = ceilf(y2 - y1);
    bool cond = fabsf(tmp - dis) > 0.35f * dis;
    if (cond) { dsum += tmp; dnum += 1.0f; dis = dsum / fmaxf(dnum, 1.0f); }
    float start_raw = last_y - 1.8f * dis;
    float end_f   = rintf(start_raw + 1.8f * dis);  // jnp.round = rint (half-to-even)
    float start_f = rintf(start_raw);
    int s = (int)fmaxf(start_f, 0.0f);
    int e = (int)fminf(end_f, (float)(HH - 1));
    bool valid = (s <= e) && (end_f >= 0.0f) && (start_f <= (float)(HH - 1));
    Tup acc = {-INFINITY, 0.0f, 0.0f, 0.0f};
    if (valid) acc = merge_rows(F + (size_t)i * HH, s, e);  // block-uniform branch
    finalize(acc, s, e, valid, ax, ay);
    st[2 * i] = ax; st[2 * i + 1] = ay;
  }

  if (threadIdx.x < 22) out[threadIdx.x] = st[threadIdx.x];
}

extern "C" void kernel_launch(void* const* d_in, const int* in_sizes, int n_in,
                              void* d_out, int out_size, void* d_ws, size_t ws_size,
                              hipStream_t stream) {
  const float* heat = (const float*)d_in[0];
  float* out = (float*)d_out;
  float* ws = (float*)d_ws;
  hipLaunchKernelGGL(k_rows_all, dim3(11 * HH), dim3(NB), 0, stream, heat, ws);
  hipLaunchKernelGGL(k_chain, dim3(1), dim3(NB), 0, stream, ws, out);
}